// Round 12
// baseline (283.761 us; speedup 1.0000x reference)
//
#include <hip/hip_runtime.h>
#include <hip/hip_bf16.h>
#include <stdint.h>

typedef unsigned long long u64;
typedef __hip_bfloat16 bf16;
typedef short s8v __attribute__((ext_vector_type(8)));
typedef short s4v __attribute__((ext_vector_type(4)));
typedef float f4v __attribute__((ext_vector_type(4)));

#define B_   16
#define C_   256
#define N_   1024
#define HID_ 512

// async global->LDS, 16B per lane; dest = wave-uniform base + lane*16
#define GLD16(g, l)                                                         \
    __builtin_amdgcn_global_load_lds(                                       \
        (const __attribute__((address_space(1))) void*)(g),                 \
        (__attribute__((address_space(3))) void*)(l), 16, 0, 0)

// counted-vmcnt barrier (T4): wait only the OLDEST loads, keep newest in
// flight across the barrier; sched_barrier stops hipcc hoisting ds_reads.
#define WAITB4() do {                                                       \
        asm volatile("s_waitcnt vmcnt(4)" ::: "memory");                    \
        __builtin_amdgcn_s_barrier();                                       \
        __builtin_amdgcn_sched_barrier(0);                                  \
    } while (0)
#define WAITB2() do {                                                       \
        asm volatile("s_waitcnt vmcnt(2)" ::: "memory");                    \
        __builtin_amdgcn_s_barrier();                                       \
        __builtin_amdgcn_sched_barrier(0);                                  \
    } while (0)
#define WAITB0() do {                                                       \
        asm volatile("s_waitcnt vmcnt(0)" ::: "memory");                    \
        __builtin_amdgcn_s_barrier();                                       \
        __builtin_amdgcn_sched_barrier(0);                                  \
    } while (0)

// fp32 -> bf16 RNE, bit-level
__device__ __forceinline__ unsigned short f2b(float f) {
    unsigned u = __float_as_uint(f);
    unsigned r = (u + 0x7FFFu + ((u >> 16) & 1u)) >> 16;
    return (unsigned short)r;
}
__device__ __forceinline__ float b2f(unsigned short s) {
    return __uint_as_float(((unsigned)s) << 16);
}
// Runtime-dtype input load: bf==1 -> bf16, bf==0 -> fp32.
__device__ __forceinline__ float ldIn(const void* p, long long i, int bf) {
    return bf ? b2f(((const unsigned short*)p)[i]) : ((const float*)p)[i];
}
__device__ __forceinline__ u64 shfl_xor_u64(u64 v, int m) {
    unsigned lo = (unsigned)v, hi = (unsigned)(v >> 32);
    lo = __shfl_xor(lo, m, 64);
    hi = __shfl_xor(hi, m, 64);
    return ((u64)hi << 32) | lo;
}

// ---------------------------------------------------------------------------
// Merged cast + prep (R11-verified).
// ---------------------------------------------------------------------------
__global__ __launch_bounds__(256)
void cast_prep(const void* xp, const void* w1, const void* wg, const void* w2,
    const void* fc1_b, const void* bn1_g, const void* bn1_b, const void* bn1_m, const void* bn1_v,
    const void* gc_b,  const void* gbn_g, const void* gbn_b, const void* gbn_m, const void* gbn_v,
    const void* bn2_g, const void* bn2_b, const void* bn2_m, const void* bn2_v,
    const void* fc2_b, const void* bn3_g, const void* bn3_b, const void* bn3_m, const void* bn3_v,
    short* W1h, short* W1l, short* Wgb, short* W2b,
    int* flags, float* s1, float* t1, float* Sg, float* Tg, float* s3, float* t3,
    float* x2)
{
    __shared__ int sf;
    int t = threadIdx.x;
    if (t == 0) {
        const unsigned short* u = (const unsigned short*)xp;
        int cnt = 0;
        for (int i = 0; i < 64; ++i) {
            int e = (u[2 * i] >> 7) & 0xFF;
            cnt += (e >= 87 && e <= 167);
        }
        sf = (cnt >= 48) ? 1 : 0;
    }
    __syncthreads();
    int inf = sf;
    int bid = blockIdx.x;

    if (bid == 1792) {
        if (t == 0) flags[0] = inf;
        int i = t;   // 0..255
        {
            float g = ldIn(bn1_g, i, inf), bb = ldIn(bn1_b, i, inf);
            float m = ldIn(bn1_m, i, inf), v  = ldIn(bn1_v, i, inf);
            float s = g / sqrtf(v + 1e-5f);
            s1[i] = s;
            t1[i] = (ldIn(fc1_b, i, inf) - m) * s + bb;

            float g3 = ldIn(bn3_g, i, inf), b3 = ldIn(bn3_b, i, inf);
            float m3 = ldIn(bn3_m, i, inf), v3 = ldIn(bn3_v, i, inf);
            float ss3 = g3 / sqrtf(v3 + 1e-5f);
            s3[i] = ss3;
            t3[i] = (ldIn(fc2_b, i, inf) - m3) * ss3 + b3;
        }
        #pragma unroll
        for (int pass = 0; pass < 2; ++pass) {
            int j = t + pass * 256;   // 0..511
            float gg = ldIn(gbn_g, j, inf), gb = ldIn(gbn_b, j, inf);
            float gm = ldIn(gbn_m, j, inf), gv = ldIn(gbn_v, j, inf);
            float sg = gg / sqrtf(gv + 1e-5f);
            float g2 = ldIn(bn2_g, j, inf), b2 = ldIn(bn2_b, j, inf);
            float m2 = ldIn(bn2_m, j, inf), v2 = ldIn(bn2_v, j, inf);
            float s2 = g2 / sqrtf(v2 + 1e-5f);
            Sg[j] = sg * s2;
            Tg[j] = ((ldIn(gc_b, j, inf) - gm) * sg + gb - m2) * s2 + b2;
        }
        return;
    }

    if (bid < 64) x2[bid * 256 + t] = 0.f;

    long long i = (long long)bid * 256 + t;
    if (i < 65536) {
        float f = ldIn(w1, i, inf);
        unsigned short h = f2b(f);
        W1h[i] = (short)h;
        W1l[i] = (short)f2b(f - b2f(h));
    } else if (i < 65536 + 262144) {
        long long j = i - 65536;
        Wgb[j] = (short)f2b(ldIn(wg, j, inf));
    } else {
        long long j = i - 327680;
        W2b[j] = (short)f2b(ldIn(w2, j, inf));
    }
}

// ---------------------------------------------------------------------------
// transpose_split_x: x[b][c][n] -> xth/xtl[b][n][c] (bf16 hi/lo split).
// ---------------------------------------------------------------------------
__global__ __launch_bounds__(256)
void transpose_split_x(const void* __restrict__ X, short* __restrict__ xth,
                       short* __restrict__ xtl, const int* __restrict__ flags)
{
    __shared__ float tile[64][68];
    int inf = flags[0];
    int t = threadIdx.x;
    int n0 = blockIdx.x * 64, c0 = blockIdx.y * 64, b = blockIdx.z;

    #pragma unroll
    for (int rr = 0; rr < 4; ++rr) {
        int cl = (t >> 4) + rr * 16;
        int nl = (t & 15) * 4;
        long long g = ((long long)b * C_ + c0 + cl) * N_ + n0 + nl;
        if (inf) {
            s4v v = *(const s4v*)((const short*)X + g);
            tile[cl][nl + 0] = b2f((unsigned short)v[0]);
            tile[cl][nl + 1] = b2f((unsigned short)v[1]);
            tile[cl][nl + 2] = b2f((unsigned short)v[2]);
            tile[cl][nl + 3] = b2f((unsigned short)v[3]);
        } else {
            f4v v = *(const f4v*)((const float*)X + g);
            tile[cl][nl + 0] = v[0]; tile[cl][nl + 1] = v[1];
            tile[cl][nl + 2] = v[2]; tile[cl][nl + 3] = v[3];
        }
    }
    __syncthreads();

    int nl = t >> 2, cseg = t & 3;   // thread covers 16 c for one n
    long long base = ((long long)((b << 10) + n0 + nl)) * C_ + c0 + cseg * 16;
    s8v h0, h1, l0, l1;
    #pragma unroll
    for (int cc = 0; cc < 16; ++cc) {
        float f = tile[cseg * 16 + cc][nl];
        unsigned short h = f2b(f);
        unsigned short l = f2b(f - b2f(h));
        if (cc < 8) { h0[cc] = (short)h; l0[cc] = (short)l; }
        else        { h1[cc - 8] = (short)h; l1[cc - 8] = (short)l; }
    }
    *(s8v*)(xth + base)     = h0;
    *(s8v*)(xth + base + 8) = h1;
    *(s8v*)(xtl + base)     = l0;
    *(s8v*)(xtl + base + 8) = l1;
}

// ---------------------------------------------------------------------------
// fc1 split-MFMA v10 (R8/R10-verified): 3-slot LDS pipeline with counted
// vmcnt(4) + raw s_barrier. MFMA sequence identical -> bit-identical.
// x2: exactly 2 commutative atomic partials per row (order-independent).
// ---------------------------------------------------------------------------
__global__ __launch_bounds__(256)
void fc1_mfma(const short* __restrict__ W1h, const short* __restrict__ W1l,
              const short* __restrict__ xth, const short* __restrict__ xtl,
              const float* __restrict__ s1, const float* __restrict__ t1,
              float* __restrict__ Ft, short* __restrict__ Fhi,
              short* __restrict__ Flo, float* __restrict__ x2)
{
    __shared__ __align__(16) char ldsbuf[49152];   // 3 slots x (8KB hi + 8KB lo)

    int t = threadIdx.x;
    int n0 = blockIdx.x * 64, o0 = blockIdx.y * 128, b = blockIdx.z;
    int wv = t >> 6, lane = t & 63, ln15 = t & 15, quad = (t >> 4) & 3;

    int csw = (((lane & 3) ^ ((lane >> 3) & 3))) * 8;
    const short* gAh = W1h + (long long)(o0 + wv * 32 + (lane >> 2)) * C_ + csw;
    const short* gAl = W1l + (long long)(o0 + wv * 32 + (lane >> 2)) * C_ + csw;
    int slotofs = wv * 32 * 32;

#define FC1_STAGE(kc_) do {                                                   \
        short* base_ = (short*)(ldsbuf + ((kc_) % 3) * 16384);                \
        short* dh = base_ + slotofs;                                          \
        short* dl = base_ + 4096 + slotofs;                                   \
        GLD16(gAh + (kc_) * 32,            dh);                               \
        GLD16(gAh + (kc_) * 32 + 16 * C_,  dh + 16 * 32);                     \
        GLD16(gAl + (kc_) * 32,            dl);                               \
        GLD16(gAl + (kc_) * 32 + 16 * C_,  dl + 16 * 32);                     \
    } while (0)

    FC1_STAGE(0);

    // persistent B fragments (issued between S(0) and S(1) so vmcnt(4)
    // at kc=0 drains them + S(0) while S(1) stays in flight)
    s8v xh[8], xl[8];
    {
        long long xoff = (long long)((b << 10) + n0 + wv * 16 + ln15) * C_ + quad * 8;
        #pragma unroll
        for (int kc = 0; kc < 8; ++kc) {
            xh[kc] = *(const s8v*)(xth + xoff + kc * 32);
            xl[kc] = *(const s8v*)(xtl + xoff + kc * 32);
        }
    }

    FC1_STAGE(1);

    f4v acc[8];
    #pragma unroll
    for (int i = 0; i < 8; ++i) acc[i] = 0.f;

    int roff = (quad ^ ((ln15 >> 1) & 3)) * 8;

    #pragma unroll
    for (int kc = 0; kc < 8; ++kc) {
        if (kc < 7) WAITB4(); else WAITB0();
        if (kc < 6) FC1_STAGE(kc + 2);
        const short* Ah_c = (const short*)(ldsbuf + (kc % 3) * 16384);
        const short* Al_c = Ah_c + 4096;
        #pragma unroll
        for (int i = 0; i < 8; ++i) {
            s8v wh8 = *(const s8v*)&Ah_c[(i * 16 + ln15) * 32 + roff];
            s8v wl8 = *(const s8v*)&Al_c[(i * 16 + ln15) * 32 + roff];
            acc[i] = __builtin_amdgcn_mfma_f32_16x16x32_bf16(wh8, xh[kc], acc[i], 0, 0, 0);
            acc[i] = __builtin_amdgcn_mfma_f32_16x16x32_bf16(wh8, xl[kc], acc[i], 0, 0, 0);
            acc[i] = __builtin_amdgcn_mfma_f32_16x16x32_bf16(wl8, xh[kc], acc[i], 0, 0, 0);
        }
    }
#undef FC1_STAGE

    int n = n0 + wv * 16 + ln15;
    long long nb = (long long)(b << 10) + n;
    float p2 = 0.f;
    #pragma unroll
    for (int i = 0; i < 8; ++i) {
        int ob = o0 + i * 16 + quad * 4;
        f4v f;
        s4v hi, lo;
        #pragma unroll
        for (int r = 0; r < 4; ++r) {
            float v = acc[i][r] * s1[ob + r] + t1[ob + r];
            f[r] = v;
            unsigned short h = f2b(v);
            hi[r] = (short)h;
            lo[r] = (short)f2b(v - b2f(h));
            p2 += v * v;
        }
        *(f4v*)(Ft  + nb * C_ + ob) = f;
        *(s4v*)(Fhi + nb * C_ + ob) = hi;
        *(s4v*)(Flo + nb * C_ + ob) = lo;
    }
    p2 += __shfl_xor(p2, 16, 64);
    p2 += __shfl_xor(p2, 32, 64);
    if (quad == 0) atomicAdd(&x2[nb], p2);
}

// ---------------------------------------------------------------------------
// Fused gram + top-9 v6 (exact R3-verified form, 59.4 us): GLD16 2-slot dbuf
// + chunk XOR swizzle, x2s in LDS, LDS merge tree.
// ---------------------------------------------------------------------------
__global__ __launch_bounds__(256)
void gram_topk(const short* __restrict__ Fhi, const short* __restrict__ Flo,
               const float* __restrict__ x2, u64* __restrict__ Part)
{
    __shared__ __align__(16) char ldsbuf[33280];
    float* x2s = (float*)(ldsbuf + 32768);
    u64*   mrg  = (u64*)(ldsbuf);            // 64*4*9*8 = 18432 B
    u64*   mrg2 = (u64*)(ldsbuf + 20480);    // 128*9*8  =  9216 B

    int t = threadIdx.x;
    int q0 = blockIdx.x * 64, mq = blockIdx.y, b = blockIdx.z;
    int wv = t >> 6, lane = t & 63, ln15 = t & 15, quad = (t >> 4) & 3;

    int csw = (((lane & 3) ^ ((lane >> 3) & 3))) * 8;
    const short* gAh = Fhi + (long long)((b << 10) + mq * 128 + wv * 32 + (lane >> 2)) * C_ + csw;
    const short* gAl = Flo + (long long)((b << 10) + mq * 128 + wv * 32 + (lane >> 2)) * C_ + csw;
    short* lH0 = (short*)(ldsbuf)           + wv * 32 * 32;
    short* lL0 = (short*)(ldsbuf + 8192)    + wv * 32 * 32;
    short* lH1 = (short*)(ldsbuf + 16384)   + wv * 32 * 32;
    short* lL1 = (short*)(ldsbuf + 24576)   + wv * 32 * 32;

#define GRAM_STAGE(kc_, bi_) do {                                             \
        short* dh = (bi_) ? lH1 : lH0;                                        \
        short* dl = (bi_) ? lL1 : lL0;                                        \
        GLD16(gAh + (kc_) * 32,            dh);                               \
        GLD16(gAh + (kc_) * 32 + 16 * C_,  dh + 16 * 32);                     \
        GLD16(gAl + (kc_) * 32,            dl);                               \
        GLD16(gAl + (kc_) * 32 + 16 * C_,  dl + 16 * 32);                     \
    } while (0)

    GRAM_STAGE(0, 0);

    if (t < 128) x2s[t] = x2[(b << 10) + mq * 128 + t];

    // persistent Q fragments
    s8v qh[8], ql[8];
    {
        long long qoff = (long long)((b << 10) + q0 + wv * 16 + ln15) * C_ + quad * 8;
        #pragma unroll
        for (int kc = 0; kc < 8; ++kc) {
            qh[kc] = *(const s8v*)(Fhi + qoff + kc * 32);
            ql[kc] = *(const s8v*)(Flo + qoff + kc * 32);
        }
    }

    f4v acc[8];
    #pragma unroll
    for (int i = 0; i < 8; ++i) acc[i] = 0.f;

    int roff = (quad ^ ((ln15 >> 1) & 3)) * 8;

    __syncthreads();   // buf0 + x2s ready

    #pragma unroll
    for (int kc = 0; kc < 8; ++kc) {
        if (kc < 7) GRAM_STAGE(kc + 1, (kc + 1) & 1);
        const short* Ah_c = (const short*)(ldsbuf + (kc & 1) * 16384);
        const short* Al_c = Ah_c + 4096;
        #pragma unroll
        for (int i = 0; i < 8; ++i) {
            s8v mh = *(const s8v*)&Ah_c[(i * 16 + ln15) * 32 + roff];
            s8v ml = *(const s8v*)&Al_c[(i * 16 + ln15) * 32 + roff];
            acc[i] = __builtin_amdgcn_mfma_f32_16x16x32_bf16(mh, qh[kc], acc[i], 0, 0, 0);
            acc[i] = __builtin_amdgcn_mfma_f32_16x16x32_bf16(mh, ql[kc], acc[i], 0, 0, 0);
            acc[i] = __builtin_amdgcn_mfma_f32_16x16x32_bf16(ml, qh[kc], acc[i], 0, 0, 0);
        }
        __syncthreads();
    }
#undef GRAM_STAGE

    u64 l[9];
    #pragma unroll
    for (int i = 0; i < 9; ++i) l[i] = ~0ULL;
    #pragma unroll
    for (int i = 0; i < 8; ++i) {
        #pragma unroll
        for (int r = 0; r < 4; ++r) {
            int mloc = i * 16 + quad * 4 + r;
            float d = x2s[mloc] - 2.f * acc[i][r];
            unsigned u = __float_as_uint(d);
            u = (u & 0x80000000u) ? ~u : (u | 0x80000000u);
            u64 key = ((u64)u << 32) | (unsigned)(mq * 128 + mloc);
            if (key < l[8]) {
                u64 x = key;
                #pragma unroll
                for (int jj = 0; jj < 9; ++jj) {
                    u64 lo2 = l[jj] < x ? l[jj] : x;
                    u64 hi2 = l[jj] < x ? x : l[jj];
                    l[jj] = lo2; x = hi2;
                }
            }
        }
    }

    __syncthreads();
    {
        int qloc = wv * 16 + ln15;
        #pragma unroll
        for (int k = 0; k < 9; ++k) mrg[(qloc * 4 + quad) * 9 + k] = l[k];
    }
    __syncthreads();
    if (t < 128) {
        int r = t >> 1, pr = t & 1;
        const u64* LA = &mrg[(r * 4 + pr * 2) * 9];
        const u64* LB = LA + 9;
        int ia = 0, ib = 0;
        u64* Po = &mrg2[(r * 2 + pr) * 9];
        #pragma unroll
        for (int k = 0; k < 9; ++k) {
            u64 va = LA[ia], vb = LB[ib];
            bool ta = va < vb;
            Po[k] = ta ? va : vb;
            ia += ta; ib += !ta;
        }
    }
    __syncthreads();
    if (t < 64) {
        const u64* LA = &mrg2[(t * 2) * 9];
        const u64* LB = LA + 9;
        int ia = 0, ib = 0;
        u64* P = Part + (((long long)((b << 10) + q0 + t)) * 8 + mq) * 9;
        #pragma unroll
        for (int k = 0; k < 9; ++k) {
            u64 va = LA[ia], vb = LB[ib];
            bool ta = va < vb;
            P[k] = ta ? va : vb;
            ia += ta; ib += !ta;
        }
    }
}

// ---------------------------------------------------------------------------
// build_Mt v2: R3-verified body + XCD-affinity work remap. Blocks handling
// batch b land on XCD b&7 (assuming dispatch XCD = linear_wgid % 8), so each
// XCD's 4MB L2 sees only 2 Ft slabs (2 MB) instead of all 16 MB -> the 9x
// re-read gather hits L2. Bijective index permutation; numerics identical.
// ---------------------------------------------------------------------------
__global__ __launch_bounds__(256)
void build_Mt(const float* __restrict__ Ft, const u64* __restrict__ Part,
              short* __restrict__ Mt)
{
    int t = threadIdx.x;
    int wv = t >> 6, lane = t & 63;
    int L = blockIdx.x + (blockIdx.y << 8);   // 0..4095
    int xcd = L & 7;
    int j = L >> 3;                            // 0..511
    int b = xcd + ((j >> 8) << 3);             // {xcd, xcd+8}
    int nx = j & 255;
    int n = nx * 4 + wv;
    long long nb = (long long)(b << 10) + n;

    const u64* Lp = Part + nb * 72 + (long long)(lane & 7) * 9;
    u64 l[9];
    #pragma unroll
    for (int k = 0; k < 9; ++k) l[k] = Lp[k];
    #pragma unroll
    for (int s = 1; s <= 4; s <<= 1) {
        u64 p[9];
        #pragma unroll
        for (int k = 0; k < 9; ++k) p[k] = shfl_xor_u64(l[k], s);
        #pragma unroll
        for (int k = 0; k < 9; ++k) {
            u64 x = p[k];
            if (x < l[8]) {
                #pragma unroll
                for (int jj = 0; jj < 9; ++jj) {
                    u64 lo2 = l[jj] < x ? l[jj] : x;
                    u64 hi2 = l[jj] < x ? x : l[jj];
                    l[jj] = lo2; x = hi2;
                }
            }
        }
    }

    int c0 = lane * 4;
    f4v f = *(const f4v*)(Ft + nb * C_ + c0);
    f4v mx = {-3.4e38f, -3.4e38f, -3.4e38f, -3.4e38f};
    #pragma unroll
    for (int k = 0; k < 9; ++k) {
        int id = (int)(l[k] & 0xFFFFFFFFu);
        f4v g = *(const f4v*)(Ft + ((long long)(b << 10) + id) * C_ + c0);
        mx[0] = fmaxf(mx[0], g[0]); mx[1] = fmaxf(mx[1], g[1]);
        mx[2] = fmaxf(mx[2], g[2]); mx[3] = fmaxf(mx[3], g[3]);
    }
    s8v m8;
    #pragma unroll
    for (int r = 0; r < 4; ++r) {
        m8[2 * r]     = (short)f2b(f[r]);
        m8[2 * r + 1] = (short)f2b(mx[r] - f[r]);
    }
    *(s8v*)(Mt + nb * (2 * C_) + 2 * c0) = m8;
}

// ---------------------------------------------------------------------------
// MFMA GEMM v11 (R11-verified): 4-slot counted-vmcnt pipeline.
// ---------------------------------------------------------------------------
template<int EPI, int K_>
__global__ __launch_bounds__(256)
void mfma_gemm(const short* __restrict__ A, const short* __restrict__ Bm,
               void* __restrict__ Out, const float* __restrict__ scale,
               const float* __restrict__ bias, const void* __restrict__ resid,
               const int* __restrict__ flags, int Odim)
{
    __shared__ __align__(16) char ldsbuf[32768];   // 4 slots x 8KB

    int t = threadIdx.x, b = blockIdx.z;
    int n0 = blockIdx.x * 64, o0 = blockIdx.y * 128;
    int wv = t >> 6, lane = t & 63, ln15 = t & 15, quad = (t >> 4) & 3;

    int csw = (((lane & 3) ^ ((lane >> 3) & 3))) * 8;
    const short* gA = A + (long long)(o0 + wv * 32 + (lane >> 2)) * K_ + csw;
    int slotofs = wv * 32 * 32;

#define GEMM_STAGE(kc_) do {                                                  \
        short* d = (short*)(ldsbuf + ((kc_) & 3) * 8192) + slotofs;           \
        GLD16(gA + (kc_) * 32,            d);                                 \
        GLD16(gA + (kc_) * 32 + 16 * K_,  d + 16 * 32);                       \
    } while (0)

    GEMM_STAGE(0);

    constexpr int NKC = K_ / 32;
    s8v bfr[NKC];
    {
        long long boff = (long long)((b << 10) + n0 + wv * 16 + ln15) * K_ + quad * 8;
        #pragma unroll
        for (int kc = 0; kc < NKC; ++kc)
            bfr[kc] = *(const s8v*)(Bm + boff + kc * 32);
    }

    GEMM_STAGE(1);
    GEMM_STAGE(2);

    f4v acc[8];
    #pragma unroll
    for (int i = 0; i < 8; ++i) acc[i] = 0.f;

    int roff = (quad ^ ((ln15 >> 1) & 3)) * 8;

    #pragma unroll
    for (int kc = 0; kc < NKC; ++kc) {
        if (kc < NKC - 2) WAITB4();
        else if (kc == NKC - 2) WAITB2();
        else WAITB0();
        if (kc < NKC - 3) GEMM_STAGE(kc + 3);
        const short* Ac = (const short*)(ldsbuf + (kc & 3) * 8192);
        #pragma unroll
        for (int i = 0; i < 8; ++i) {
            s8v a = *(const s8v*)&Ac[(i * 16 + ln15) * 32 + roff];
            acc[i] = __builtin_amdgcn_mfma_f32_16x16x32_bf16(a, bfr[kc], acc[i], 0, 0, 0);
        }
    }
#undef GEMM_STAGE

    int inf = flags[0];
    int n = n0 + wv * 16 + ln15;
    #pragma unroll
    for (int i = 0; i < 8; ++i) {
        int ob = o0 + i * 16 + quad * 4;
        if (EPI == 0) {
            s4v g;
            #pragma unroll
            for (int r = 0; r < 4; ++r) {
                float val = acc[i][r] * scale[ob + r] + bias[ob + r];
                val = 0.5f * val * (1.0f + erff(val * 0.70710678118654752f));
                g[r] = (short)f2b(val);
            }
            *(s4v*)((short*)Out + ((long long)((b << 10) + n)) * Odim + ob) = g;
        } else {
            #pragma unroll
            for (int r = 0; r < 4; ++r) {
                int o = ob + r;
                long long oi = ((long long)b * Odim + o) * N_ + n;
                ((float*)Out)[oi] = acc[i][r] * scale[o] + bias[o] + ldIn(resid, oi, inf);
            }
        }
    }
}

// ---------------------------------------------------------------------------
extern "C" void kernel_launch(void* const* d_in, const int* in_sizes, int n_in,
                              void* d_out, int out_size, void* d_ws, size_t ws_size,
                              hipStream_t stream)
{
    const void* p[23];
    if (n_in >= 23 && in_sizes[0] != 4194304 && in_sizes[22] == 4194304) {
        const int amap[23] = {
            22, 13, 12, 1, 0, 2, 3,
            21, 20, 17, 16, 18, 19,
            5, 4, 6, 7,
            15, 14, 9, 8, 10, 11 };
        for (int i = 0; i < 23; ++i) p[i] = d_in[amap[i]];
    } else {
        for (int i = 0; i < 23; ++i) p[i] = d_in[i];
    }

    const void* x     = p[0];
    const void* fc1_w = p[1];
    const void* fc1_b = p[2];
    const void* bn1_g = p[3];
    const void* bn1_b = p[4];
    const void* bn1_m = p[5];
    const void* bn1_v = p[6];
    const void* gc_w  = p[7];
    const void* gc_b  = p[8];
    const void* gbn_g = p[9];
    const void* gbn_b = p[10];
    const void* gbn_m = p[11];
    const void* gbn_v = p[12];
    const void* bn2_g = p[13];
    const void* bn2_b = p[14];
    const void* bn2_m = p[15];
    const void* bn2_v = p[16];
    const void* fc2_w = p[17];
    const void* fc2_b = p[18];
    const void* bn3_g = p[19];
    const void* bn3_b = p[20];
    const void* bn3_m = p[21];
    const void* bn3_v = p[22];

    char* ws = (char*)d_ws;
    size_t off = 0;
    int*   flags = (int*)ws;
    float* s1 = (float*)(ws + 256);
    float* t1 = s1 + 256;
    float* s3 = t1 + 256;
    float* t3 = s3 + 256;
    float* Sg = t3 + 256;
    float* Tg = Sg + 512;
    off = 16384;
    short* W1h   = (short*)(ws + off); off += (size_t)C_ * C_ * 2;          // 128 KiB
    short* W1l   = (short*)(ws + off); off += (size_t)C_ * C_ * 2;          // 128 KiB
    short* Wgb   = (short*)(ws + off); off += (size_t)HID_ * 2 * C_ * 2;    // 512 KiB
    short* W2b   = (short*)(ws + off); off += (size_t)C_ * HID_ * 2;        // 256 KiB
    short* xth   = (short*)(ws + off); off += (size_t)B_ * N_ * C_ * 2;     // 8 MiB
    short* xtl   = (short*)(ws + off); off += (size_t)B_ * N_ * C_ * 2;     // 8 MiB
    float* Ft    = (float*)(ws + off); off += (size_t)B_ * N_ * C_ * 4;     // 16 MiB
    short* Fhi   = (short*)(ws + off); off += (size_t)B_ * N_ * C_ * 2;     // 8 MiB
    short* Flo   = (short*)(ws + off); off += (size_t)B_ * N_ * C_ * 2;     // 8 MiB
    float* x2    = (float*)(ws + off); off += (size_t)B_ * N_ * 4;          // 64 KiB
    u64*   Part  = (u64*)  (ws + off); off += (size_t)B_ * N_ * 8 * 9 * 8;  // 9 MiB
    short* Mt    = (short*)(ws + off); off += (size_t)B_ * N_ * 2 * C_ * 2; // 16 MiB
    short* Gt    = (short*)(ws + off); off += (size_t)B_ * N_ * HID_ * 2;   // 16 MiB

    cast_prep<<<1793, 256, 0, stream>>>(x, fc1_w, gc_w, fc2_w,
        fc1_b, bn1_g, bn1_b, bn1_m, bn1_v,
        gc_b, gbn_g, gbn_b, gbn_m, gbn_v,
        bn2_g, bn2_b, bn2_m, bn2_v,
        fc2_b, bn3_g, bn3_b, bn3_m, bn3_v,
        W1h, W1l, Wgb, W2b,
        flags, s1, t1, Sg, Tg, s3, t3, x2);

    transpose_split_x<<<dim3(16, 4, 16), 256, 0, stream>>>(x, xth, xtl, flags);

    fc1_mfma<<<dim3(16, 2, 16), 256, 0, stream>>>(
        W1h, W1l, xth, xtl, s1, t1, Ft, Fhi, Flo, x2);

    gram_topk<<<dim3(16, 8, 16), 256, 0, stream>>>(Fhi, Flo, x2, Part);

    build_Mt<<<dim3(256, 16), 256, 0, stream>>>(Ft, Part, Mt);

    mfma_gemm<0, 512><<<dim3(16, 4, 16), 256, 0, stream>>>(
        Wgb, Mt, Gt, Sg, Tg, nullptr, flags, HID_);

    mfma_gemm<1, 512><<<dim3(16, 2, 16), 256, 0, stream>>>(
        W2b, Gt, d_out, s3, t3, x, flags, C_);
}

// Round 13
// 278.544 us; speedup vs baseline: 1.0187x; 1.0187x over previous
//
#include <hip/hip_runtime.h>
#include <hip/hip_bf16.h>
#include <stdint.h>

typedef unsigned long long u64;
typedef __hip_bfloat16 bf16;
typedef short s8v __attribute__((ext_vector_type(8)));
typedef short s4v __attribute__((ext_vector_type(4)));
typedef float f4v __attribute__((ext_vector_type(4)));

#define B_   16
#define C_   256
#define N_   1024
#define HID_ 512

// async global->LDS, 16B per lane; dest = wave-uniform base + lane*16
#define GLD16(g, l)                                                         \
    __builtin_amdgcn_global_load_lds(                                       \
        (const __attribute__((address_space(1))) void*)(g),                 \
        (__attribute__((address_space(3))) void*)(l), 16, 0, 0)

// counted-vmcnt barrier (T4): wait only the OLDEST loads, keep newest in
// flight across the barrier; sched_barrier stops hipcc hoisting ds_reads.
#define WAITB4() do {                                                       \
        asm volatile("s_waitcnt vmcnt(4)" ::: "memory");                    \
        __builtin_amdgcn_s_barrier();                                       \
        __builtin_amdgcn_sched_barrier(0);                                  \
    } while (0)
#define WAITB2() do {                                                       \
        asm volatile("s_waitcnt vmcnt(2)" ::: "memory");                    \
        __builtin_amdgcn_s_barrier();                                       \
        __builtin_amdgcn_sched_barrier(0);                                  \
    } while (0)
#define WAITB0() do {                                                       \
        asm volatile("s_waitcnt vmcnt(0)" ::: "memory");                    \
        __builtin_amdgcn_s_barrier();                                       \
        __builtin_amdgcn_sched_barrier(0);                                  \
    } while (0)

// fp32 -> bf16 RNE, bit-level
__device__ __forceinline__ unsigned short f2b(float f) {
    unsigned u = __float_as_uint(f);
    unsigned r = (u + 0x7FFFu + ((u >> 16) & 1u)) >> 16;
    return (unsigned short)r;
}
__device__ __forceinline__ float b2f(unsigned short s) {
    return __uint_as_float(((unsigned)s) << 16);
}
// Runtime-dtype input load: bf==1 -> bf16, bf==0 -> fp32.
__device__ __forceinline__ float ldIn(const void* p, long long i, int bf) {
    return bf ? b2f(((const unsigned short*)p)[i]) : ((const float*)p)[i];
}
__device__ __forceinline__ u64 shfl_xor_u64(u64 v, int m) {
    unsigned lo = (unsigned)v, hi = (unsigned)(v >> 32);
    lo = __shfl_xor(lo, m, 64);
    hi = __shfl_xor(hi, m, 64);
    return ((u64)hi << 32) | lo;
}

// ---------------------------------------------------------------------------
// Merged cast + prep (R11-verified).
// ---------------------------------------------------------------------------
__global__ __launch_bounds__(256)
void cast_prep(const void* xp, const void* w1, const void* wg, const void* w2,
    const void* fc1_b, const void* bn1_g, const void* bn1_b, const void* bn1_m, const void* bn1_v,
    const void* gc_b,  const void* gbn_g, const void* gbn_b, const void* gbn_m, const void* gbn_v,
    const void* bn2_g, const void* bn2_b, const void* bn2_m, const void* bn2_v,
    const void* fc2_b, const void* bn3_g, const void* bn3_b, const void* bn3_m, const void* bn3_v,
    short* W1h, short* W1l, short* Wgb, short* W2b,
    int* flags, float* s1, float* t1, float* Sg, float* Tg, float* s3, float* t3,
    float* x2)
{
    __shared__ int sf;
    int t = threadIdx.x;
    if (t == 0) {
        const unsigned short* u = (const unsigned short*)xp;
        int cnt = 0;
        for (int i = 0; i < 64; ++i) {
            int e = (u[2 * i] >> 7) & 0xFF;
            cnt += (e >= 87 && e <= 167);
        }
        sf = (cnt >= 48) ? 1 : 0;
    }
    __syncthreads();
    int inf = sf;
    int bid = blockIdx.x;

    if (bid == 1792) {
        if (t == 0) flags[0] = inf;
        int i = t;   // 0..255
        {
            float g = ldIn(bn1_g, i, inf), bb = ldIn(bn1_b, i, inf);
            float m = ldIn(bn1_m, i, inf), v  = ldIn(bn1_v, i, inf);
            float s = g / sqrtf(v + 1e-5f);
            s1[i] = s;
            t1[i] = (ldIn(fc1_b, i, inf) - m) * s + bb;

            float g3 = ldIn(bn3_g, i, inf), b3 = ldIn(bn3_b, i, inf);
            float m3 = ldIn(bn3_m, i, inf), v3 = ldIn(bn3_v, i, inf);
            float ss3 = g3 / sqrtf(v3 + 1e-5f);
            s3[i] = ss3;
            t3[i] = (ldIn(fc2_b, i, inf) - m3) * ss3 + b3;
        }
        #pragma unroll
        for (int pass = 0; pass < 2; ++pass) {
            int j = t + pass * 256;   // 0..511
            float gg = ldIn(gbn_g, j, inf), gb = ldIn(gbn_b, j, inf);
            float gm = ldIn(gbn_m, j, inf), gv = ldIn(gbn_v, j, inf);
            float sg = gg / sqrtf(gv + 1e-5f);
            float g2 = ldIn(bn2_g, j, inf), b2 = ldIn(bn2_b, j, inf);
            float m2 = ldIn(bn2_m, j, inf), v2 = ldIn(bn2_v, j, inf);
            float s2 = g2 / sqrtf(v2 + 1e-5f);
            Sg[j] = sg * s2;
            Tg[j] = ((ldIn(gc_b, j, inf) - gm) * sg + gb - m2) * s2 + b2;
        }
        return;
    }

    if (bid < 64) x2[bid * 256 + t] = 0.f;

    long long i = (long long)bid * 256 + t;
    if (i < 65536) {
        float f = ldIn(w1, i, inf);
        unsigned short h = f2b(f);
        W1h[i] = (short)h;
        W1l[i] = (short)f2b(f - b2f(h));
    } else if (i < 65536 + 262144) {
        long long j = i - 65536;
        Wgb[j] = (short)f2b(ldIn(wg, j, inf));
    } else {
        long long j = i - 327680;
        W2b[j] = (short)f2b(ldIn(w2, j, inf));
    }
}

// ---------------------------------------------------------------------------
// transpose_split_x: x[b][c][n] -> xth/xtl[b][n][c] (bf16 hi/lo split).
// ---------------------------------------------------------------------------
__global__ __launch_bounds__(256)
void transpose_split_x(const void* __restrict__ X, short* __restrict__ xth,
                       short* __restrict__ xtl, const int* __restrict__ flags)
{
    __shared__ float tile[64][68];
    int inf = flags[0];
    int t = threadIdx.x;
    int n0 = blockIdx.x * 64, c0 = blockIdx.y * 64, b = blockIdx.z;

    #pragma unroll
    for (int rr = 0; rr < 4; ++rr) {
        int cl = (t >> 4) + rr * 16;
        int nl = (t & 15) * 4;
        long long g = ((long long)b * C_ + c0 + cl) * N_ + n0 + nl;
        if (inf) {
            s4v v = *(const s4v*)((const short*)X + g);
            tile[cl][nl + 0] = b2f((unsigned short)v[0]);
            tile[cl][nl + 1] = b2f((unsigned short)v[1]);
            tile[cl][nl + 2] = b2f((unsigned short)v[2]);
            tile[cl][nl + 3] = b2f((unsigned short)v[3]);
        } else {
            f4v v = *(const f4v*)((const float*)X + g);
            tile[cl][nl + 0] = v[0]; tile[cl][nl + 1] = v[1];
            tile[cl][nl + 2] = v[2]; tile[cl][nl + 3] = v[3];
        }
    }
    __syncthreads();

    int nl = t >> 2, cseg = t & 3;   // thread covers 16 c for one n
    long long base = ((long long)((b << 10) + n0 + nl)) * C_ + c0 + cseg * 16;
    s8v h0, h1, l0, l1;
    #pragma unroll
    for (int cc = 0; cc < 16; ++cc) {
        float f = tile[cseg * 16 + cc][nl];
        unsigned short h = f2b(f);
        unsigned short l = f2b(f - b2f(h));
        if (cc < 8) { h0[cc] = (short)h; l0[cc] = (short)l; }
        else        { h1[cc - 8] = (short)h; l1[cc - 8] = (short)l; }
    }
    *(s8v*)(xth + base)     = h0;
    *(s8v*)(xth + base + 8) = h1;
    *(s8v*)(xtl + base)     = l0;
    *(s8v*)(xtl + base + 8) = l1;
}

// ---------------------------------------------------------------------------
// fc1 split-MFMA v10 (R8/R10-verified): 3-slot LDS pipeline with counted
// vmcnt(4) + raw s_barrier. MFMA sequence identical -> bit-identical.
// x2: exactly 2 commutative atomic partials per row (order-independent).
// ---------------------------------------------------------------------------
__global__ __launch_bounds__(256)
void fc1_mfma(const short* __restrict__ W1h, const short* __restrict__ W1l,
              const short* __restrict__ xth, const short* __restrict__ xtl,
              const float* __restrict__ s1, const float* __restrict__ t1,
              float* __restrict__ Ft, short* __restrict__ Fhi,
              short* __restrict__ Flo, float* __restrict__ x2)
{
    __shared__ __align__(16) char ldsbuf[49152];   // 3 slots x (8KB hi + 8KB lo)

    int t = threadIdx.x;
    int n0 = blockIdx.x * 64, o0 = blockIdx.y * 128, b = blockIdx.z;
    int wv = t >> 6, lane = t & 63, ln15 = t & 15, quad = (t >> 4) & 3;

    int csw = (((lane & 3) ^ ((lane >> 3) & 3))) * 8;
    const short* gAh = W1h + (long long)(o0 + wv * 32 + (lane >> 2)) * C_ + csw;
    const short* gAl = W1l + (long long)(o0 + wv * 32 + (lane >> 2)) * C_ + csw;
    int slotofs = wv * 32 * 32;

#define FC1_STAGE(kc_) do {                                                   \
        short* base_ = (short*)(ldsbuf + ((kc_) % 3) * 16384);                \
        short* dh = base_ + slotofs;                                          \
        short* dl = base_ + 4096 + slotofs;                                   \
        GLD16(gAh + (kc_) * 32,            dh);                               \
        GLD16(gAh + (kc_) * 32 + 16 * C_,  dh + 16 * 32);                     \
        GLD16(gAl + (kc_) * 32,            dl);                               \
        GLD16(gAl + (kc_) * 32 + 16 * C_,  dl + 16 * 32);                     \
    } while (0)

    FC1_STAGE(0);

    // persistent B fragments (issued between S(0) and S(1) so vmcnt(4)
    // at kc=0 drains them + S(0) while S(1) stays in flight)
    s8v xh[8], xl[8];
    {
        long long xoff = (long long)((b << 10) + n0 + wv * 16 + ln15) * C_ + quad * 8;
        #pragma unroll
        for (int kc = 0; kc < 8; ++kc) {
            xh[kc] = *(const s8v*)(xth + xoff + kc * 32);
            xl[kc] = *(const s8v*)(xtl + xoff + kc * 32);
        }
    }

    FC1_STAGE(1);

    f4v acc[8];
    #pragma unroll
    for (int i = 0; i < 8; ++i) acc[i] = 0.f;

    int roff = (quad ^ ((ln15 >> 1) & 3)) * 8;

    #pragma unroll
    for (int kc = 0; kc < 8; ++kc) {
        if (kc < 7) WAITB4(); else WAITB0();
        if (kc < 6) FC1_STAGE(kc + 2);
        const short* Ah_c = (const short*)(ldsbuf + (kc % 3) * 16384);
        const short* Al_c = Ah_c + 4096;
        #pragma unroll
        for (int i = 0; i < 8; ++i) {
            s8v wh8 = *(const s8v*)&Ah_c[(i * 16 + ln15) * 32 + roff];
            s8v wl8 = *(const s8v*)&Al_c[(i * 16 + ln15) * 32 + roff];
            acc[i] = __builtin_amdgcn_mfma_f32_16x16x32_bf16(wh8, xh[kc], acc[i], 0, 0, 0);
            acc[i] = __builtin_amdgcn_mfma_f32_16x16x32_bf16(wh8, xl[kc], acc[i], 0, 0, 0);
            acc[i] = __builtin_amdgcn_mfma_f32_16x16x32_bf16(wl8, xh[kc], acc[i], 0, 0, 0);
        }
    }
#undef FC1_STAGE

    int n = n0 + wv * 16 + ln15;
    long long nb = (long long)(b << 10) + n;
    float p2 = 0.f;
    #pragma unroll
    for (int i = 0; i < 8; ++i) {
        int ob = o0 + i * 16 + quad * 4;
        f4v f;
        s4v hi, lo;
        #pragma unroll
        for (int r = 0; r < 4; ++r) {
            float v = acc[i][r] * s1[ob + r] + t1[ob + r];
            f[r] = v;
            unsigned short h = f2b(v);
            hi[r] = (short)h;
            lo[r] = (short)f2b(v - b2f(h));
            p2 += v * v;
        }
        *(f4v*)(Ft  + nb * C_ + ob) = f;
        *(s4v*)(Fhi + nb * C_ + ob) = hi;
        *(s4v*)(Flo + nb * C_ + ob) = lo;
    }
    p2 += __shfl_xor(p2, 16, 64);
    p2 += __shfl_xor(p2, 32, 64);
    if (quad == 0) atomicAdd(&x2[nb], p2);
}

// ---------------------------------------------------------------------------
// Fused gram + top-9 v6 (exact R3-verified form, 59.4 us): GLD16 2-slot dbuf
// + chunk XOR swizzle, x2s in LDS, LDS merge tree.
// ---------------------------------------------------------------------------
__global__ __launch_bounds__(256)
void gram_topk(const short* __restrict__ Fhi, const short* __restrict__ Flo,
               const float* __restrict__ x2, u64* __restrict__ Part)
{
    __shared__ __align__(16) char ldsbuf[33280];
    float* x2s = (float*)(ldsbuf + 32768);
    u64*   mrg  = (u64*)(ldsbuf);            // 64*4*9*8 = 18432 B
    u64*   mrg2 = (u64*)(ldsbuf + 20480);    // 128*9*8  =  9216 B

    int t = threadIdx.x;
    int q0 = blockIdx.x * 64, mq = blockIdx.y, b = blockIdx.z;
    int wv = t >> 6, lane = t & 63, ln15 = t & 15, quad = (t >> 4) & 3;

    int csw = (((lane & 3) ^ ((lane >> 3) & 3))) * 8;
    const short* gAh = Fhi + (long long)((b << 10) + mq * 128 + wv * 32 + (lane >> 2)) * C_ + csw;
    const short* gAl = Flo + (long long)((b << 10) + mq * 128 + wv * 32 + (lane >> 2)) * C_ + csw;
    short* lH0 = (short*)(ldsbuf)           + wv * 32 * 32;
    short* lL0 = (short*)(ldsbuf + 8192)    + wv * 32 * 32;
    short* lH1 = (short*)(ldsbuf + 16384)   + wv * 32 * 32;
    short* lL1 = (short*)(ldsbuf + 24576)   + wv * 32 * 32;

#define GRAM_STAGE(kc_, bi_) do {                                             \
        short* dh = (bi_) ? lH1 : lH0;                                        \
        short* dl = (bi_) ? lL1 : lL0;                                        \
        GLD16(gAh + (kc_) * 32,            dh);                               \
        GLD16(gAh + (kc_) * 32 + 16 * C_,  dh + 16 * 32);                     \
        GLD16(gAl + (kc_) * 32,            dl);                               \
        GLD16(gAl + (kc_) * 32 + 16 * C_,  dl + 16 * 32);                     \
    } while (0)

    GRAM_STAGE(0, 0);

    if (t < 128) x2s[t] = x2[(b << 10) + mq * 128 + t];

    // persistent Q fragments
    s8v qh[8], ql[8];
    {
        long long qoff = (long long)((b << 10) + q0 + wv * 16 + ln15) * C_ + quad * 8;
        #pragma unroll
        for (int kc = 0; kc < 8; ++kc) {
            qh[kc] = *(const s8v*)(Fhi + qoff + kc * 32);
            ql[kc] = *(const s8v*)(Flo + qoff + kc * 32);
        }
    }

    f4v acc[8];
    #pragma unroll
    for (int i = 0; i < 8; ++i) acc[i] = 0.f;

    int roff = (quad ^ ((ln15 >> 1) & 3)) * 8;

    __syncthreads();   // buf0 + x2s ready

    #pragma unroll
    for (int kc = 0; kc < 8; ++kc) {
        if (kc < 7) GRAM_STAGE(kc + 1, (kc + 1) & 1);
        const short* Ah_c = (const short*)(ldsbuf + (kc & 1) * 16384);
        const short* Al_c = Ah_c + 4096;
        #pragma unroll
        for (int i = 0; i < 8; ++i) {
            s8v mh = *(const s8v*)&Ah_c[(i * 16 + ln15) * 32 + roff];
            s8v ml = *(const s8v*)&Al_c[(i * 16 + ln15) * 32 + roff];
            acc[i] = __builtin_amdgcn_mfma_f32_16x16x32_bf16(mh, qh[kc], acc[i], 0, 0, 0);
            acc[i] = __builtin_amdgcn_mfma_f32_16x16x32_bf16(mh, ql[kc], acc[i], 0, 0, 0);
            acc[i] = __builtin_amdgcn_mfma_f32_16x16x32_bf16(ml, qh[kc], acc[i], 0, 0, 0);
        }
        __syncthreads();
    }
#undef GRAM_STAGE

    u64 l[9];
    #pragma unroll
    for (int i = 0; i < 9; ++i) l[i] = ~0ULL;
    #pragma unroll
    for (int i = 0; i < 8; ++i) {
        #pragma unroll
        for (int r = 0; r < 4; ++r) {
            int mloc = i * 16 + quad * 4 + r;
            float d = x2s[mloc] - 2.f * acc[i][r];
            unsigned u = __float_as_uint(d);
            u = (u & 0x80000000u) ? ~u : (u | 0x80000000u);
            u64 key = ((u64)u << 32) | (unsigned)(mq * 128 + mloc);
            if (key < l[8]) {
                u64 x = key;
                #pragma unroll
                for (int jj = 0; jj < 9; ++jj) {
                    u64 lo2 = l[jj] < x ? l[jj] : x;
                    u64 hi2 = l[jj] < x ? x : l[jj];
                    l[jj] = lo2; x = hi2;
                }
            }
        }
    }

    __syncthreads();
    {
        int qloc = wv * 16 + ln15;
        #pragma unroll
        for (int k = 0; k < 9; ++k) mrg[(qloc * 4 + quad) * 9 + k] = l[k];
    }
    __syncthreads();
    if (t < 128) {
        int r = t >> 1, pr = t & 1;
        const u64* LA = &mrg[(r * 4 + pr * 2) * 9];
        const u64* LB = LA + 9;
        int ia = 0, ib = 0;
        u64* Po = &mrg2[(r * 2 + pr) * 9];
        #pragma unroll
        for (int k = 0; k < 9; ++k) {
            u64 va = LA[ia], vb = LB[ib];
            bool ta = va < vb;
            Po[k] = ta ? va : vb;
            ia += ta; ib += !ta;
        }
    }
    __syncthreads();
    if (t < 64) {
        const u64* LA = &mrg2[(t * 2) * 9];
        const u64* LB = LA + 9;
        int ia = 0, ib = 0;
        u64* P = Part + (((long long)((b << 10) + q0 + t)) * 8 + mq) * 9;
        #pragma unroll
        for (int k = 0; k < 9; ++k) {
            u64 va = LA[ia], vb = LB[ib];
            bool ta = va < vb;
            P[k] = ta ? va : vb;
            ia += ta; ib += !ta;
        }
    }
}

// ---------------------------------------------------------------------------
// build_Mt + fused 8-list merge (R3/R11-verified linear-grid form).
// ---------------------------------------------------------------------------
__global__ __launch_bounds__(256)
void build_Mt(const float* __restrict__ Ft, const u64* __restrict__ Part,
              short* __restrict__ Mt)
{
    int t = threadIdx.x;
    int wv = t >> 6, lane = t & 63;
    int n = blockIdx.x * 4 + wv;
    int b = blockIdx.y;
    long long nb = (long long)(b << 10) + n;

    const u64* L = Part + nb * 72 + (long long)(lane & 7) * 9;
    u64 l[9];
    #pragma unroll
    for (int k = 0; k < 9; ++k) l[k] = L[k];
    #pragma unroll
    for (int s = 1; s <= 4; s <<= 1) {
        u64 p[9];
        #pragma unroll
        for (int k = 0; k < 9; ++k) p[k] = shfl_xor_u64(l[k], s);
        #pragma unroll
        for (int k = 0; k < 9; ++k) {
            u64 x = p[k];
            if (x < l[8]) {
                #pragma unroll
                for (int jj = 0; jj < 9; ++jj) {
                    u64 lo2 = l[jj] < x ? l[jj] : x;
                    u64 hi2 = l[jj] < x ? x : l[jj];
                    l[jj] = lo2; x = hi2;
                }
            }
        }
    }

    int c0 = lane * 4;
    f4v f = *(const f4v*)(Ft + nb * C_ + c0);
    f4v mx = {-3.4e38f, -3.4e38f, -3.4e38f, -3.4e38f};
    #pragma unroll
    for (int k = 0; k < 9; ++k) {
        int id = (int)(l[k] & 0xFFFFFFFFu);
        f4v g = *(const f4v*)(Ft + ((long long)(b << 10) + id) * C_ + c0);
        mx[0] = fmaxf(mx[0], g[0]); mx[1] = fmaxf(mx[1], g[1]);
        mx[2] = fmaxf(mx[2], g[2]); mx[3] = fmaxf(mx[3], g[3]);
    }
    s8v m8;
    #pragma unroll
    for (int r = 0; r < 4; ++r) {
        m8[2 * r]     = (short)f2b(f[r]);
        m8[2 * r + 1] = (short)f2b(mx[r] - f[r]);
    }
    *(s8v*)(Mt + nb * (2 * C_) + 2 * c0) = m8;
}

// ---------------------------------------------------------------------------
// MFMA GEMM v11 (R11-verified): 4-slot counted-vmcnt pipeline.
// ---------------------------------------------------------------------------
template<int EPI, int K_>
__global__ __launch_bounds__(256)
void mfma_gemm(const short* __restrict__ A, const short* __restrict__ Bm,
               void* __restrict__ Out, const float* __restrict__ scale,
               const float* __restrict__ bias, const void* __restrict__ resid,
               const int* __restrict__ flags, int Odim)
{
    __shared__ __align__(16) char ldsbuf[32768];   // 4 slots x 8KB

    int t = threadIdx.x, b = blockIdx.z;
    int n0 = blockIdx.x * 64, o0 = blockIdx.y * 128;
    int wv = t >> 6, lane = t & 63, ln15 = t & 15, quad = (t >> 4) & 3;

    int csw = (((lane & 3) ^ ((lane >> 3) & 3))) * 8;
    const short* gA = A + (long long)(o0 + wv * 32 + (lane >> 2)) * K_ + csw;
    int slotofs = wv * 32 * 32;

#define GEMM_STAGE(kc_) do {                                                  \
        short* d = (short*)(ldsbuf + ((kc_) & 3) * 8192) + slotofs;           \
        GLD16(gA + (kc_) * 32,            d);                                 \
        GLD16(gA + (kc_) * 32 + 16 * K_,  d + 16 * 32);                       \
    } while (0)

    GEMM_STAGE(0);

    constexpr int NKC = K_ / 32;
    s8v bfr[NKC];
    {
        long long boff = (long long)((b << 10) + n0 + wv * 16 + ln15) * K_ + quad * 8;
        #pragma unroll
        for (int kc = 0; kc < NKC; ++kc)
            bfr[kc] = *(const s8v*)(Bm + boff + kc * 32);
    }

    GEMM_STAGE(1);
    GEMM_STAGE(2);

    f4v acc[8];
    #pragma unroll
    for (int i = 0; i < 8; ++i) acc[i] = 0.f;

    int roff = (quad ^ ((ln15 >> 1) & 3)) * 8;

    #pragma unroll
    for (int kc = 0; kc < NKC; ++kc) {
        if (kc < NKC - 2) WAITB4();
        else if (kc == NKC - 2) WAITB2();
        else WAITB0();
        if (kc < NKC - 3) GEMM_STAGE(kc + 3);
        const short* Ac = (const short*)(ldsbuf + (kc & 3) * 8192);
        #pragma unroll
        for (int i = 0; i < 8; ++i) {
            s8v a = *(const s8v*)&Ac[(i * 16 + ln15) * 32 + roff];
            acc[i] = __builtin_amdgcn_mfma_f32_16x16x32_bf16(a, bfr[kc], acc[i], 0, 0, 0);
        }
    }
#undef GEMM_STAGE

    int inf = flags[0];
    int n = n0 + wv * 16 + ln15;
    #pragma unroll
    for (int i = 0; i < 8; ++i) {
        int ob = o0 + i * 16 + quad * 4;
        if (EPI == 0) {
            s4v g;
            #pragma unroll
            for (int r = 0; r < 4; ++r) {
                float val = acc[i][r] * scale[ob + r] + bias[ob + r];
                val = 0.5f * val * (1.0f + erff(val * 0.70710678118654752f));
                g[r] = (short)f2b(val);
            }
            *(s4v*)((short*)Out + ((long long)((b << 10) + n)) * Odim + ob) = g;
        } else {
            #pragma unroll
            for (int r = 0; r < 4; ++r) {
                int o = ob + r;
                long long oi = ((long long)b * Odim + o) * N_ + n;
                ((float*)Out)[oi] = acc[i][r] * scale[o] + bias[o] + ldIn(resid, oi, inf);
            }
        }
    }
}

// ---------------------------------------------------------------------------
extern "C" void kernel_launch(void* const* d_in, const int* in_sizes, int n_in,
                              void* d_out, int out_size, void* d_ws, size_t ws_size,
                              hipStream_t stream)
{
    const void* p[23];
    if (n_in >= 23 && in_sizes[0] != 4194304 && in_sizes[22] == 4194304) {
        const int amap[23] = {
            22, 13, 12, 1, 0, 2, 3,
            21, 20, 17, 16, 18, 19,
            5, 4, 6, 7,
            15, 14, 9, 8, 10, 11 };
        for (int i = 0; i < 23; ++i) p[i] = d_in[amap[i]];
    } else {
        for (int i = 0; i < 23; ++i) p[i] = d_in[i];
    }

    const void* x     = p[0];
    const void* fc1_w = p[1];
    const void* fc1_b = p[2];
    const void* bn1_g = p[3];
    const void* bn1_b = p[4];
    const void* bn1_m = p[5];
    const void* bn1_v = p[6];
    const void* gc_w  = p[7];
    const void* gc_b  = p[8];
    const void* gbn_g = p[9];
    const void* gbn_b = p[10];
    const void* gbn_m = p[11];
    const void* gbn_v = p[12];
    const void* bn2_g = p[13];
    const void* bn2_b = p[14];
    const void* bn2_m = p[15];
    const void* bn2_v = p[16];
    const void* fc2_w = p[17];
    const void* fc2_b = p[18];
    const void* bn3_g = p[19];
    const void* bn3_b = p[20];
    const void* bn3_m = p[21];
    const void* bn3_v = p[22];

    char* ws = (char*)d_ws;
    size_t off = 0;
    int*   flags = (int*)ws;
    float* s1 = (float*)(ws + 256);
    float* t1 = s1 + 256;
    float* s3 = t1 + 256;
    float* t3 = s3 + 256;
    float* Sg = t3 + 256;
    float* Tg = Sg + 512;
    off = 16384;
    short* W1h   = (short*)(ws + off); off += (size_t)C_ * C_ * 2;          // 128 KiB
    short* W1l   = (short*)(ws + off); off += (size_t)C_ * C_ * 2;          // 128 KiB
    short* Wgb   = (short*)(ws + off); off += (size_t)HID_ * 2 * C_ * 2;    // 512 KiB
    short* W2b   = (short*)(ws + off); off += (size_t)C_ * HID_ * 2;        // 256 KiB
    short* xth   = (short*)(ws + off); off += (size_t)B_ * N_ * C_ * 2;     // 8 MiB
    short* xtl   = (short*)(ws + off); off += (size_t)B_ * N_ * C_ * 2;     // 8 MiB
    float* Ft    = (float*)(ws + off); off += (size_t)B_ * N_ * C_ * 4;     // 16 MiB
    short* Fhi   = (short*)(ws + off); off += (size_t)B_ * N_ * C_ * 2;     // 8 MiB
    short* Flo   = (short*)(ws + off); off += (size_t)B_ * N_ * C_ * 2;     // 8 MiB
    float* x2    = (float*)(ws + off); off += (size_t)B_ * N_ * 4;          // 64 KiB
    u64*   Part  = (u64*)  (ws + off); off += (size_t)B_ * N_ * 8 * 9 * 8;  // 9 MiB
    short* Mt    = (short*)(ws + off); off += (size_t)B_ * N_ * 2 * C_ * 2; // 16 MiB
    short* Gt    = (short*)(ws + off); off += (size_t)B_ * N_ * HID_ * 2;   // 16 MiB

    cast_prep<<<1793, 256, 0, stream>>>(x, fc1_w, gc_w, fc2_w,
        fc1_b, bn1_g, bn1_b, bn1_m, bn1_v,
        gc_b, gbn_g, gbn_b, gbn_m, gbn_v,
        bn2_g, bn2_b, bn2_m, bn2_v,
        fc2_b, bn3_g, bn3_b, bn3_m, bn3_v,
        W1h, W1l, Wgb, W2b,
        flags, s1, t1, Sg, Tg, s3, t3, x2);

    transpose_split_x<<<dim3(16, 4, 16), 256, 0, stream>>>(x, xth, xtl, flags);

    fc1_mfma<<<dim3(16, 2, 16), 256, 0, stream>>>(
        W1h, W1l, xth, xtl, s1, t1, Ft, Fhi, Flo, x2);

    gram_topk<<<dim3(16, 8, 16), 256, 0, stream>>>(Fhi, Flo, x2, Part);

    build_Mt<<<dim3(256, 16), 256, 0, stream>>>(Ft, Part, Mt);

    mfma_gemm<0, 512><<<dim3(16, 4, 16), 256, 0, stream>>>(
        Wgb, Mt, Gt, Sg, Tg, nullptr, flags, HID_);

    mfma_gemm<1, 512><<<dim3(16, 2, 16), 256, 0, stream>>>(
        W2b, Gt, d_out, s3, t3, x, flags, C_);
}